// Round 2
// baseline (7325.840 us; speedup 1.0000x reference)
//
#include <hip/hip_runtime.h>

// x0[N,128] = pept[N,512] @ Wp[512,128] + bp   (f32)
__global__ __launch_bounds__(256) void k_proj(
    const float* __restrict__ pept, const float* __restrict__ Wp,
    const float* __restrict__ bp, float* __restrict__ x0, int N)
{
  __shared__ float xs[16][516];  // +4 pad: rows land on banks 4 apart
  const int row0 = blockIdx.x * 16;
  const int t = threadIdx.x;
  for (int idx = t; idx < 16 * 128; idx += 256) {   // 16 rows x 128 float4
    int r = idx >> 7, v = idx & 127;
    if (row0 + r < N) {
      *reinterpret_cast<float4*>(&xs[r][v * 4]) =
          *reinterpret_cast<const float4*>(pept + (size_t)(row0 + r) * 512 + v * 4);
    }
  }
  __syncthreads();
  const int row = t >> 4, cg = t & 15, c0 = cg * 8;
  if (row0 + row >= N) return;
  float acc[8];
#pragma unroll
  for (int j = 0; j < 8; ++j) acc[j] = bp[c0 + j];
  for (int k = 0; k < 512; ++k) {
    float h = xs[row][k];
    float4 w0 = *reinterpret_cast<const float4*>(Wp + (size_t)k * 128 + c0);
    float4 w1 = *reinterpret_cast<const float4*>(Wp + (size_t)k * 128 + c0 + 4);
    acc[0] += h * w0.x; acc[1] += h * w0.y; acc[2] += h * w0.z; acc[3] += h * w0.w;
    acc[4] += h * w1.x; acc[5] += h * w1.y; acc[6] += h * w1.z; acc[7] += h * w1.w;
  }
  float4* op = reinterpret_cast<float4*>(x0 + (size_t)(row0 + row) * 128 + c0);
  op[0] = make_float4(acc[0], acc[1], acc[2], acc[3]);
  op[1] = make_float4(acc[4], acc[5], acc[6], acc[7]);
}

// agg[dst] += relu(x[src] + emb[attr])  -- 32 lanes per edge, 4 floats each
__global__ __launch_bounds__(256) void k_edge(
    const float* __restrict__ x, const int* __restrict__ src,
    const int* __restrict__ dst, const int* __restrict__ attr,
    const float* __restrict__ emb, float* __restrict__ agg, int nE)
{
  long long g = (long long)blockIdx.x * 256 + threadIdx.x;
  int e = (int)(g >> 5);
  if (e >= nE) return;
  int lane = (int)(g & 31);
  int s = src[e], d = dst[e], a = attr[e];
  float4 xv = *reinterpret_cast<const float4*>(x + (size_t)s * 128 + lane * 4);
  float4 ev = *reinterpret_cast<const float4*>(emb + (size_t)a * 128 + lane * 4);
  float* ap = agg + (size_t)d * 128 + lane * 4;
  float m;
  m = xv.x + ev.x; if (m > 0.f) atomicAdd(ap + 0, m);
  m = xv.y + ev.y; if (m > 0.f) atomicAdd(ap + 1, m);
  m = xv.z + ev.z; if (m > 0.f) atomicAdd(ap + 2, m);
  m = xv.w + ev.w; if (m > 0.f) atomicAdd(ap + 3, m);
}

// MODE 0: out = relu((xin + agg) @ W + bias)          (gemm1 of the MLP)
// MODE 1: out = xin @ W + bias + xres                 (gemm2 + residual)
template <int MODE>
__global__ __launch_bounds__(256) void k_mlp(
    const float* __restrict__ xin, const float* __restrict__ agg,
    const float* __restrict__ W, const float* __restrict__ bias,
    const float* __restrict__ xres, float* __restrict__ out, int N)
{
  __shared__ float hs[32][132];  // +4 pad: rows on banks 4 apart
  const int row0 = blockIdx.x * 32;
  const int t = threadIdx.x;
  for (int idx = t; idx < 32 * 32; idx += 256) {   // 32 rows x 32 float4
    int r = idx >> 5, v = idx & 31;
    if (row0 + r < N) {
      float4 hv = *reinterpret_cast<const float4*>(xin + (size_t)(row0 + r) * 128 + v * 4);
      if (MODE == 0) {
        float4 av = *reinterpret_cast<const float4*>(agg + (size_t)(row0 + r) * 128 + v * 4);
        hv.x += av.x; hv.y += av.y; hv.z += av.z; hv.w += av.w;
      }
      *reinterpret_cast<float4*>(&hs[r][v * 4]) = hv;
    }
  }
  __syncthreads();
  const int row = t >> 3, cg = t & 7, c0 = cg * 16;
  if (row0 + row >= N) return;
  float acc[16];
#pragma unroll
  for (int j = 0; j < 16; ++j) acc[j] = bias[c0 + j];
  for (int k = 0; k < 128; ++k) {
    float h = hs[row][k];
    float4 w0 = *reinterpret_cast<const float4*>(W + (size_t)k * 128 + c0);
    float4 w1 = *reinterpret_cast<const float4*>(W + (size_t)k * 128 + c0 + 4);
    float4 w2 = *reinterpret_cast<const float4*>(W + (size_t)k * 128 + c0 + 8);
    float4 w3 = *reinterpret_cast<const float4*>(W + (size_t)k * 128 + c0 + 12);
    acc[0]  += h * w0.x; acc[1]  += h * w0.y; acc[2]  += h * w0.z; acc[3]  += h * w0.w;
    acc[4]  += h * w1.x; acc[5]  += h * w1.y; acc[6]  += h * w1.z; acc[7]  += h * w1.w;
    acc[8]  += h * w2.x; acc[9]  += h * w2.y; acc[10] += h * w2.z; acc[11] += h * w2.w;
    acc[12] += h * w3.x; acc[13] += h * w3.y; acc[14] += h * w3.z; acc[15] += h * w3.w;
  }
  if (MODE == 0) {
#pragma unroll
    for (int j = 0; j < 16; ++j) acc[j] = fmaxf(acc[j], 0.f);
  } else {
    const float4* rp = reinterpret_cast<const float4*>(xres + (size_t)(row0 + row) * 128 + c0);
    float4 r0 = rp[0], r1 = rp[1], r2 = rp[2], r3 = rp[3];
    acc[0]  += r0.x; acc[1]  += r0.y; acc[2]  += r0.z; acc[3]  += r0.w;
    acc[4]  += r1.x; acc[5]  += r1.y; acc[6]  += r1.z; acc[7]  += r1.w;
    acc[8]  += r2.x; acc[9]  += r2.y; acc[10] += r2.z; acc[11] += r2.w;
    acc[12] += r3.x; acc[13] += r3.y; acc[14] += r3.z; acc[15] += r3.w;
  }
  float4* op = reinterpret_cast<float4*>(out + (size_t)(row0 + row) * 128 + c0);
  op[0] = make_float4(acc[0],  acc[1],  acc[2],  acc[3]);
  op[1] = make_float4(acc[4],  acc[5],  acc[6],  acc[7]);
  op[2] = make_float4(acc[8],  acc[9],  acc[10], acc[11]);
  op[3] = make_float4(acc[12], acc[13], acc[14], acc[15]);
}

extern "C" void kernel_launch(void* const* d_in, const int* in_sizes, int n_in,
                              void* d_out, int out_size, void* d_ws, size_t ws_size,
                              hipStream_t stream)
{
  const float* pept  = (const float*)d_in[0];
  const int*   eidx  = (const int*)d_in[1];
  const int*   eattr = (const int*)d_in[2];
  const float* Wp  = (const float*)d_in[3];
  const float* bp  = (const float*)d_in[4];
  const float* emb = (const float*)d_in[5];
  // d_in[6] = cls_token, d_in[7] = cls_edge: provably dead for the output (CLS
  // node is never a source of any edge and row N is dropped) -> skipped.
  const float* W1a = (const float*)d_in[8];
  const float* b1a = (const float*)d_in[9];
  const float* W2a = (const float*)d_in[10];
  const float* b2a = (const float*)d_in[11];
  const float* W1b = (const float*)d_in[12];
  const float* b1b = (const float*)d_in[13];
  const float* W2b = (const float*)d_in[14];
  const float* b2b = (const float*)d_in[15];

  const int N = in_sizes[0] / 512;
  const int E = in_sizes[1] / 2;
  const int* srcp = eidx;
  const int* dstp = eidx + E;

  char* ws = (char*)d_ws;
  const size_t rowBytes = (size_t)N * 128 * 4;
  float* agg = (float*)ws;                       // [N,128] f32
  float* x0  = (float*)(ws + rowBytes);          // [N,128] f32
  float* tb  = (float*)(ws + 2 * rowBytes);      // [N,128] f32 (MLP hidden)
  float* x1  = (float*)d_out;                    // layer-a output lives in d_out
  float* outp = (float*)d_out;

  const int gProj = (N + 15) / 16;
  const int gRows = (N + 31) / 32;
  const int gEdge = (int)(((long long)E * 32 + 255) / 256);

  hipLaunchKernelGGL(k_proj, dim3(gProj), dim3(256), 0, stream, pept, Wp, bp, x0, N);

  // ---- layer a ----
  hipMemsetAsync(agg, 0, rowBytes, stream);
  hipLaunchKernelGGL(k_edge, dim3(gEdge), dim3(256), 0, stream,
                     x0, srcp, dstp, eattr, emb, agg, E);
  hipLaunchKernelGGL(k_mlp<0>, dim3(gRows), dim3(256), 0, stream,
                     x0, agg, W1a, b1a, (const float*)nullptr, tb, N);
  hipLaunchKernelGGL(k_mlp<1>, dim3(gRows), dim3(256), 0, stream,
                     tb, (const float*)nullptr, W2a, b2a, x0, x1, N);

  // ---- layer b ----
  hipMemsetAsync(agg, 0, rowBytes, stream);
  hipLaunchKernelGGL(k_edge, dim3(gEdge), dim3(256), 0, stream,
                     x1, srcp, dstp, eattr, emb, agg, E);
  hipLaunchKernelGGL(k_mlp<0>, dim3(gRows), dim3(256), 0, stream,
                     x1, agg, W1b, b1b, (const float*)nullptr, tb, N);
  hipLaunchKernelGGL(k_mlp<1>, dim3(gRows), dim3(256), 0, stream,
                     tb, (const float*)nullptr, W2b, b2b, x1, outp, N);
}

// Round 3
// 2976.006 us; speedup vs baseline: 2.4616x; 2.4616x over previous
//
#include <hip/hip_runtime.h>

// ---------------- GEMM kernels (unchanged from round 2) ----------------

// x0[N,128] = pept[N,512] @ Wp[512,128] + bp   (f32)
__global__ __launch_bounds__(256) void k_proj(
    const float* __restrict__ pept, const float* __restrict__ Wp,
    const float* __restrict__ bp, float* __restrict__ x0, int N)
{
  __shared__ float xs[16][516];
  const int row0 = blockIdx.x * 16;
  const int t = threadIdx.x;
  for (int idx = t; idx < 16 * 128; idx += 256) {
    int r = idx >> 7, v = idx & 127;
    if (row0 + r < N) {
      *reinterpret_cast<float4*>(&xs[r][v * 4]) =
          *reinterpret_cast<const float4*>(pept + (size_t)(row0 + r) * 512 + v * 4);
    }
  }
  __syncthreads();
  const int row = t >> 4, cg = t & 15, c0 = cg * 8;
  if (row0 + row >= N) return;
  float acc[8];
#pragma unroll
  for (int j = 0; j < 8; ++j) acc[j] = bp[c0 + j];
  for (int k = 0; k < 512; ++k) {
    float h = xs[row][k];
    float4 w0 = *reinterpret_cast<const float4*>(Wp + (size_t)k * 128 + c0);
    float4 w1 = *reinterpret_cast<const float4*>(Wp + (size_t)k * 128 + c0 + 4);
    acc[0] += h * w0.x; acc[1] += h * w0.y; acc[2] += h * w0.z; acc[3] += h * w0.w;
    acc[4] += h * w1.x; acc[5] += h * w1.y; acc[6] += h * w1.z; acc[7] += h * w1.w;
  }
  float4* op = reinterpret_cast<float4*>(x0 + (size_t)(row0 + row) * 128 + c0);
  op[0] = make_float4(acc[0], acc[1], acc[2], acc[3]);
  op[1] = make_float4(acc[4], acc[5], acc[6], acc[7]);
}

// MODE 0: out = relu((xin + agg) @ W + bias)
// MODE 1: out = xin @ W + bias + xres
template <int MODE>
__global__ __launch_bounds__(256) void k_mlp(
    const float* __restrict__ xin, const float* __restrict__ agg,
    const float* __restrict__ W, const float* __restrict__ bias,
    const float* __restrict__ xres, float* __restrict__ out, int N)
{
  __shared__ float hs[32][132];
  const int row0 = blockIdx.x * 32;
  const int t = threadIdx.x;
  for (int idx = t; idx < 32 * 32; idx += 256) {
    int r = idx >> 5, v = idx & 31;
    if (row0 + r < N) {
      float4 hv = *reinterpret_cast<const float4*>(xin + (size_t)(row0 + r) * 128 + v * 4);
      if (MODE == 0) {
        float4 av = *reinterpret_cast<const float4*>(agg + (size_t)(row0 + r) * 128 + v * 4);
        hv.x += av.x; hv.y += av.y; hv.z += av.z; hv.w += av.w;
      }
      *reinterpret_cast<float4*>(&hs[r][v * 4]) = hv;
    }
  }
  __syncthreads();
  const int row = t >> 3, cg = t & 7, c0 = cg * 16;
  if (row0 + row >= N) return;
  float acc[16];
#pragma unroll
  for (int j = 0; j < 16; ++j) acc[j] = bias[c0 + j];
  for (int k = 0; k < 128; ++k) {
    float h = hs[row][k];
    float4 w0 = *reinterpret_cast<const float4*>(W + (size_t)k * 128 + c0);
    float4 w1 = *reinterpret_cast<const float4*>(W + (size_t)k * 128 + c0 + 4);
    float4 w2 = *reinterpret_cast<const float4*>(W + (size_t)k * 128 + c0 + 8);
    float4 w3 = *reinterpret_cast<const float4*>(W + (size_t)k * 128 + c0 + 12);
    acc[0]  += h * w0.x; acc[1]  += h * w0.y; acc[2]  += h * w0.z; acc[3]  += h * w0.w;
    acc[4]  += h * w1.x; acc[5]  += h * w1.y; acc[6]  += h * w1.z; acc[7]  += h * w1.w;
    acc[8]  += h * w2.x; acc[9]  += h * w2.y; acc[10] += h * w2.z; acc[11] += h * w2.w;
    acc[12] += h * w3.x; acc[13] += h * w3.y; acc[14] += h * w3.z; acc[15] += h * w3.w;
  }
  if (MODE == 0) {
#pragma unroll
    for (int j = 0; j < 16; ++j) acc[j] = fmaxf(acc[j], 0.f);
  } else {
    const float4* rp = reinterpret_cast<const float4*>(xres + (size_t)(row0 + row) * 128 + c0);
    float4 r0 = rp[0], r1 = rp[1], r2 = rp[2], r3 = rp[3];
    acc[0]  += r0.x; acc[1]  += r0.y; acc[2]  += r0.z; acc[3]  += r0.w;
    acc[4]  += r1.x; acc[5]  += r1.y; acc[6]  += r1.z; acc[7]  += r1.w;
    acc[8]  += r2.x; acc[9]  += r2.y; acc[10] += r2.z; acc[11] += r2.w;
    acc[12] += r3.x; acc[13] += r3.y; acc[14] += r3.z; acc[15] += r3.w;
  }
  float4* op = reinterpret_cast<float4*>(out + (size_t)(row0 + row) * 128 + c0);
  op[0] = make_float4(acc[0],  acc[1],  acc[2],  acc[3]);
  op[1] = make_float4(acc[4],  acc[5],  acc[6],  acc[7]);
  op[2] = make_float4(acc[8],  acc[9],  acc[10], acc[11]);
  op[3] = make_float4(acc[12], acc[13], acc[14], acc[15]);
}

// ---------------- CSR build (once per launch, reused by both layers) ----------------

__global__ __launch_bounds__(256) void k_hist(
    const int* __restrict__ dst, int* __restrict__ deg, int nE)
{
  int e = blockIdx.x * 256 + threadIdx.x;
  if (e < nE) atomicAdd(&deg[dst[e]], 1);
}

// single-block exclusive scan of deg[0..N) -> off[0..N], cursor[0..N)
__global__ __launch_bounds__(1024) void k_scan(
    const int* __restrict__ deg, int* __restrict__ off,
    int* __restrict__ cursor, int N)
{
  __shared__ int ps[1024];
  const int t = threadIdx.x;
  const int C = (N + 1023) / 1024;
  const int lo = t * C, hi = min(lo + C, N);
  int s = 0;
  for (int j = lo; j < hi; ++j) s += deg[j];
  ps[t] = s;
  __syncthreads();
  // Hillis-Steele inclusive scan over 1024 partials
  for (int d = 1; d < 1024; d <<= 1) {
    int v = (t >= d) ? ps[t - d] : 0;
    __syncthreads();
    ps[t] += v;
    __syncthreads();
  }
  int run = ps[t] - s;  // exclusive prefix for this thread's chunk
  for (int j = lo; j < hi; ++j) {
    int d = deg[j];
    off[j] = run;
    cursor[j] = run;
    run += d;
  }
  if (t == 1023) off[N] = ps[1023];
}

// ep[pos] = src | (attr<<17)   (src < 2^17, attr < 100)
__global__ __launch_bounds__(256) void k_scatter(
    const int* __restrict__ src, const int* __restrict__ dst,
    const int* __restrict__ attr, int* __restrict__ cursor,
    int* __restrict__ ep, int nE)
{
  int e = blockIdx.x * 256 + threadIdx.x;
  if (e < nE) {
    int p = atomicAdd(&cursor[dst[e]], 1);
    ep[p] = src[e] | (attr[e] << 17);
  }
}

// agg[i] = sum_{e in in-edges(i)} relu(x[src_e] + emb[attr_e])
// one wave per node: 64 lanes x 2 cols, register accumulation, no atomics
__global__ __launch_bounds__(256) void k_agg(
    const float* __restrict__ x, const int* __restrict__ ep,
    const int* __restrict__ off, const float* __restrict__ emb,
    float* __restrict__ agg, int N)
{
  const int node = blockIdx.x * 4 + (threadIdx.x >> 6);
  if (node >= N) return;
  const int lane = threadIdx.x & 63;
  const int beg = off[node], end = off[node + 1];
  float ax = 0.f, ay = 0.f;
  for (int e = beg; e < end; ++e) {
    int p = ep[e];
    int s = p & 0x1FFFF;
    int a = p >> 17;
    float2 xv = *reinterpret_cast<const float2*>(x + (size_t)s * 128 + lane * 2);
    float2 ev = *reinterpret_cast<const float2*>(emb + (size_t)a * 128 + lane * 2);
    ax += fmaxf(xv.x + ev.x, 0.f);
    ay += fmaxf(xv.y + ev.y, 0.f);
  }
  float2* op = reinterpret_cast<float2*>(agg + (size_t)node * 128 + lane * 2);
  *op = make_float2(ax, ay);
}

// ---------------- launcher ----------------

extern "C" void kernel_launch(void* const* d_in, const int* in_sizes, int n_in,
                              void* d_out, int out_size, void* d_ws, size_t ws_size,
                              hipStream_t stream)
{
  const float* pept  = (const float*)d_in[0];
  const int*   eidx  = (const int*)d_in[1];
  const int*   eattr = (const int*)d_in[2];
  const float* Wp  = (const float*)d_in[3];
  const float* bp  = (const float*)d_in[4];
  const float* emb = (const float*)d_in[5];
  // d_in[6]=cls_token, d_in[7]=cls_edge: dead for the output (CLS node is never
  // a source and row N is dropped) -> skipped.
  const float* W1a = (const float*)d_in[8];
  const float* b1a = (const float*)d_in[9];
  const float* W2a = (const float*)d_in[10];
  const float* b2a = (const float*)d_in[11];
  const float* W1b = (const float*)d_in[12];
  const float* b1b = (const float*)d_in[13];
  const float* W2b = (const float*)d_in[14];
  const float* b2b = (const float*)d_in[15];

  const int N = in_sizes[0] / 512;
  const int E = in_sizes[1] / 2;
  const int* srcp = eidx;
  const int* dstp = eidx + E;

  char* ws = (char*)d_ws;
  const size_t rowBytes = (size_t)N * 128 * 4;
  float* agg = (float*)ws;                         // [N,128] f32 (also MLP hidden tb)
  float* x0  = (float*)(ws + rowBytes);            // [N,128] f32
  char*  p   = ws + 2 * rowBytes;
  int* deg    = (int*)p;            p += (size_t)(N + 1) * 4;
  int* off    = (int*)p;            p += (size_t)(N + 1) * 4;
  int* cursor = (int*)p;            p += (size_t)N * 4;
  int* ep     = (int*)p;            p += (size_t)E * 4;
  float* tb = agg;                  // alias: k_mlp<0> reads agg rows before writing them
  float* x1 = (float*)d_out;
  float* outp = (float*)d_out;

  const int gProj = (N + 15) / 16;
  const int gRows = (N + 31) / 32;
  const int gE    = (E + 255) / 256;
  const int gAgg  = (N + 3) / 4;

  hipLaunchKernelGGL(k_proj, dim3(gProj), dim3(256), 0, stream, pept, Wp, bp, x0, N);

  // CSR by dst (built once, reused by both layers)
  hipMemsetAsync(deg, 0, (size_t)(N + 1) * 4, stream);
  hipLaunchKernelGGL(k_hist, dim3(gE), dim3(256), 0, stream, dstp, deg, E);
  hipLaunchKernelGGL(k_scan, dim3(1), dim3(1024), 0, stream, deg, off, cursor, N);
  hipLaunchKernelGGL(k_scatter, dim3(gE), dim3(256), 0, stream,
                     srcp, dstp, eattr, cursor, ep, E);

  // ---- layer a ----
  hipLaunchKernelGGL(k_agg, dim3(gAgg), dim3(256), 0, stream, x0, ep, off, emb, agg, N);
  hipLaunchKernelGGL(k_mlp<0>, dim3(gRows), dim3(256), 0, stream,
                     x0, agg, W1a, b1a, (const float*)nullptr, tb, N);
  hipLaunchKernelGGL(k_mlp<1>, dim3(gRows), dim3(256), 0, stream,
                     tb, (const float*)nullptr, W2a, b2a, x0, x1, N);

  // ---- layer b ----
  hipLaunchKernelGGL(k_agg, dim3(gAgg), dim3(256), 0, stream, x1, ep, off, emb, agg, N);
  hipLaunchKernelGGL(k_mlp<0>, dim3(gRows), dim3(256), 0, stream,
                     x1, agg, W1b, b1b, (const float*)nullptr, tb, N);
  hipLaunchKernelGGL(k_mlp<1>, dim3(gRows), dim3(256), 0, stream,
                     tb, (const float*)nullptr, W2b, b2b, x1, outp, N);
}

// Round 4
// 960.906 us; speedup vs baseline: 7.6239x; 3.0971x over previous
//
#include <hip/hip_runtime.h>

typedef unsigned short u16;
typedef __attribute__((ext_vector_type(8))) short short8v;
typedef __attribute__((ext_vector_type(4))) float f32x4;

__device__ __forceinline__ u16 f2b(float f) {
  union { float fv; unsigned int i; } v; v.fv = f;
  unsigned int x = v.i;
  return (u16)((x + 0x7FFFu + ((x >> 16) & 1u)) >> 16);
}

// ---------------- weight prep: Wt[c][k] = bf16(W[k][c]) ----------------
__global__ __launch_bounds__(256) void k_prepw(
    const float* __restrict__ W, u16* __restrict__ Wt, int K, int C)
{
  int idx = blockIdx.x * 256 + threadIdx.x;
  if (idx >= K * C) return;
  int k = idx / C, c = idx - k * C;
  Wt[(size_t)c * K + k] = f2b(W[idx]);
}

// ---------------- MFMA GEMM: out[N,128] = A[N,KTOT] @ W[KTOT,128] (+bias...) ----
// STAGE: 0 = A fp32, 1 = A fp32 + agg, 2 = A bf16
// EPI:   0 = f32 out, 1 = relu -> bf16 out, 2 = (+xres) -> f32 out
template <int KTOT, int STAGE, int EPI>
__global__ __launch_bounds__(256) void k_gemm(
    const void* __restrict__ Ain, const float* __restrict__ agg,
    const u16* __restrict__ Wt, const float* __restrict__ bias,
    const float* __restrict__ xres, void* __restrict__ outp, int N)
{
  __shared__ u16 As[128 * 64];   // [r][k0..k0+64), row stride 128B, ^((r&7)<<4)
  __shared__ u16 Bs[128 * 64];   // [c][k0..k0+64), same swizzle
  const int t = threadIdx.x;
  const int row0 = blockIdx.x * 128;
  const int lane = t & 63;
  const int wave = t >> 6;
  const int wm = wave >> 1, wn = wave & 1;   // 2x2 waves, 64x64 each
  const int colg = lane & 15, rowg = lane >> 4;

  f32x4 acc[4][4];
#pragma unroll
  for (int ni = 0; ni < 4; ++ni) {
    float bc = bias[wn * 64 + ni * 16 + colg];
#pragma unroll
    for (int mi = 0; mi < 4; ++mi) acc[mi][ni] = (f32x4){bc, bc, bc, bc};
  }

  for (int k0 = 0; k0 < KTOT; k0 += 64) {
    // ---- stage A tile ----
    if (STAGE <= 1) {
      const float* A = (const float*)Ain;
#pragma unroll
      for (int i = 0; i < 8; ++i) {
        int idx = t + i * 256;            // 2048 float4 = 128 rows x 16
        int r = idx >> 4, kq = idx & 15;
        float4 v = make_float4(0.f, 0.f, 0.f, 0.f);
        if (row0 + r < N) {
          v = *reinterpret_cast<const float4*>(A + (size_t)(row0 + r) * KTOT + k0 + kq * 4);
          if (STAGE == 1) {
            float4 av = *reinterpret_cast<const float4*>(agg + (size_t)(row0 + r) * 128 + k0 + kq * 4);
            v.x += av.x; v.y += av.y; v.z += av.z; v.w += av.w;
          }
        }
        ushort4 b;
        b.x = f2b(v.x); b.y = f2b(v.y); b.z = f2b(v.z); b.w = f2b(v.w);
        int byteoff = (r * 128 + kq * 8) ^ ((r & 7) << 4);
        *reinterpret_cast<ushort4*>((char*)As + byteoff) = b;
      }
    } else {
      const u16* A = (const u16*)Ain;
#pragma unroll
      for (int i = 0; i < 4; ++i) {
        int idx = t + i * 256;            // 1024 int4 = 128 rows x 8
        int r = idx >> 3, k8 = idx & 7;
        int4 v = make_int4(0, 0, 0, 0);
        if (row0 + r < N)
          v = *reinterpret_cast<const int4*>(A + (size_t)(row0 + r) * KTOT + k0 + k8 * 8);
        int byteoff = (r * 128 + k8 * 16) ^ ((r & 7) << 4);
        *reinterpret_cast<int4*>((char*)As + byteoff) = v;
      }
    }
    // ---- stage Wt tile (bf16 [128][KTOT]) ----
#pragma unroll
    for (int i = 0; i < 4; ++i) {
      int idx = t + i * 256;
      int c = idx >> 3, k8 = idx & 7;
      int4 v = *reinterpret_cast<const int4*>(Wt + (size_t)c * KTOT + k0 + k8 * 8);
      int byteoff = (c * 128 + k8 * 16) ^ ((c & 7) << 4);
      *reinterpret_cast<int4*>((char*)Bs + byteoff) = v;
    }
    __syncthreads();
    // ---- compute ----
#pragma unroll
    for (int kk = 0; kk < 64; kk += 32) {
      short8v a[4], b[4];
#pragma unroll
      for (int mi = 0; mi < 4; ++mi) {
        int r = wm * 64 + mi * 16 + colg;
        int byteoff = (r * 128 + (kk + rowg * 8) * 2) ^ ((r & 7) << 4);
        a[mi] = *reinterpret_cast<const short8v*>((const char*)As + byteoff);
      }
#pragma unroll
      for (int ni = 0; ni < 4; ++ni) {
        int c = wn * 64 + ni * 16 + colg;
        int byteoff = (c * 128 + (kk + rowg * 8) * 2) ^ ((c & 7) << 4);
        b[ni] = *reinterpret_cast<const short8v*>((const char*)Bs + byteoff);
      }
#pragma unroll
      for (int mi = 0; mi < 4; ++mi)
#pragma unroll
        for (int ni = 0; ni < 4; ++ni)
          acc[mi][ni] = __builtin_amdgcn_mfma_f32_16x16x32_bf16(a[mi], b[ni], acc[mi][ni], 0, 0, 0);
    }
    __syncthreads();
  }

  // ---- epilogue: D lane map col = lane&15, row = (lane>>4)*4 + j ----
#pragma unroll
  for (int mi = 0; mi < 4; ++mi) {
#pragma unroll
    for (int j = 0; j < 4; ++j) {
      int row = row0 + wm * 64 + mi * 16 + rowg * 4 + j;
      if (row >= N) continue;
#pragma unroll
      for (int ni = 0; ni < 4; ++ni) {
        int col = wn * 64 + ni * 16 + colg;
        float v = acc[mi][ni][j];
        if (EPI == 1) {
          ((u16*)outp)[(size_t)row * 128 + col] = f2b(fmaxf(v, 0.f));
        } else {
          if (EPI == 2) v += xres[(size_t)row * 128 + col];
          ((float*)outp)[(size_t)row * 128 + col] = v;
        }
      }
    }
  }
}

// ---------------- CSR build ----------------
__global__ __launch_bounds__(256) void k_hist(
    const int* __restrict__ dst, int* __restrict__ deg, int nE)
{
  int e = blockIdx.x * 256 + threadIdx.x;
  if (e < nE) atomicAdd(&deg[dst[e]], 1);
}

__global__ __launch_bounds__(1024) void k_scan(
    const int* __restrict__ deg, int* __restrict__ off,
    int* __restrict__ cursor, int N)
{
  __shared__ int ps[1024];
  const int t = threadIdx.x;
  const int C = (N + 1023) / 1024;
  const int lo = t * C, hi = min(lo + C, N);
  int s = 0;
  for (int j = lo; j < hi; ++j) s += deg[j];
  ps[t] = s;
  __syncthreads();
  for (int d = 1; d < 1024; d <<= 1) {
    int v = (t >= d) ? ps[t - d] : 0;
    __syncthreads();
    ps[t] += v;
    __syncthreads();
  }
  int run = ps[t] - s;
  for (int j = lo; j < hi; ++j) {
    int d = deg[j];
    off[j] = run;
    cursor[j] = run;
    run += d;
  }
  if (t == 1023) off[N] = ps[1023];
}

__global__ __launch_bounds__(256) void k_scatter(
    const int* __restrict__ src, const int* __restrict__ dst,
    const int* __restrict__ attr, int* __restrict__ cursor,
    int* __restrict__ ep, int nE)
{
  int e = blockIdx.x * 256 + threadIdx.x;
  if (e < nE) {
    int p = atomicAdd(&cursor[dst[e]], 1);
    ep[p] = src[e] | (attr[e] << 17);
  }
}

// agg[i] = sum_{e in in-edges(i)} relu(x[src_e] + emb[attr_e]); one wave/node
__global__ __launch_bounds__(256) void k_agg(
    const float* __restrict__ x, const int* __restrict__ ep,
    const int* __restrict__ off, const float* __restrict__ emb,
    float* __restrict__ agg, int N)
{
  const int node = blockIdx.x * 4 + (threadIdx.x >> 6);
  if (node >= N) return;
  const int lane = threadIdx.x & 63;
  const int beg = off[node], end = off[node + 1];
  float ax = 0.f, ay = 0.f;
  for (int e = beg; e < end; ++e) {
    int p = ep[e];
    int s = p & 0x1FFFF;
    int a = p >> 17;
    float2 xv = *reinterpret_cast<const float2*>(x + (size_t)s * 128 + lane * 2);
    float2 ev = *reinterpret_cast<const float2*>(emb + (size_t)a * 128 + lane * 2);
    ax += fmaxf(xv.x + ev.x, 0.f);
    ay += fmaxf(xv.y + ev.y, 0.f);
  }
  float2* op = reinterpret_cast<float2*>(agg + (size_t)node * 128 + lane * 2);
  *op = make_float2(ax, ay);
}

// ---------------- launcher ----------------
extern "C" void kernel_launch(void* const* d_in, const int* in_sizes, int n_in,
                              void* d_out, int out_size, void* d_ws, size_t ws_size,
                              hipStream_t stream)
{
  const float* pept  = (const float*)d_in[0];
  const int*   eidx  = (const int*)d_in[1];
  const int*   eattr = (const int*)d_in[2];
  const float* Wp  = (const float*)d_in[3];
  const float* bp  = (const float*)d_in[4];
  const float* emb = (const float*)d_in[5];
  // d_in[6]=cls_token, d_in[7]=cls_edge: dead for the output (CLS node is never
  // a source and row N is dropped) -> skipped.
  const float* W1a = (const float*)d_in[8];
  const float* b1a = (const float*)d_in[9];
  const float* W2a = (const float*)d_in[10];
  const float* b2a = (const float*)d_in[11];
  const float* W1b = (const float*)d_in[12];
  const float* b1b = (const float*)d_in[13];
  const float* W2b = (const float*)d_in[14];
  const float* b2b = (const float*)d_in[15];

  const int N = in_sizes[0] / 512;
  const int E = in_sizes[1] / 2;
  const int* srcp = eidx;
  const int* dstp = eidx + E;

  char* ws = (char*)d_ws;
  const size_t rowBytes = (size_t)N * 128 * 4;
  float* agg = (float*)ws;                          // [N,128] f32
  float* x0  = (float*)(ws + rowBytes);             // [N,128] f32
  char*  p   = ws + 2 * rowBytes;
  u16* tbh   = (u16*)p;             p += (size_t)N * 128 * 2;   // bf16 hidden
  int* deg    = (int*)p;            p += (size_t)(N + 1) * 4;
  int* off    = (int*)p;            p += (size_t)(N + 1) * 4;
  int* cursor = (int*)p;            p += (size_t)N * 4;
  int* ep     = (int*)p;            p += (size_t)E * 4;
  u16* Wpt  = (u16*)p;              p += (size_t)512 * 128 * 2;
  u16* W1at = (u16*)p;              p += (size_t)128 * 128 * 2;
  u16* W2at = (u16*)p;              p += (size_t)128 * 128 * 2;
  u16* W1bt = (u16*)p;              p += (size_t)128 * 128 * 2;
  u16* W2bt = (u16*)p;              p += (size_t)128 * 128 * 2;
  float* x1 = (float*)d_out;
  float* outp = (float*)d_out;

  const int gGemm = (N + 127) / 128;
  const int gE    = (E + 255) / 256;
  const int gAgg  = (N + 3) / 4;

  // weight prep (once)
  hipLaunchKernelGGL(k_prepw, dim3((512 * 128 + 255) / 256), dim3(256), 0, stream, Wp,  Wpt,  512, 128);
  hipLaunchKernelGGL(k_prepw, dim3((128 * 128 + 255) / 256), dim3(256), 0, stream, W1a, W1at, 128, 128);
  hipLaunchKernelGGL(k_prepw, dim3((128 * 128 + 255) / 256), dim3(256), 0, stream, W2a, W2at, 128, 128);
  hipLaunchKernelGGL(k_prepw, dim3((128 * 128 + 255) / 256), dim3(256), 0, stream, W1b, W1bt, 128, 128);
  hipLaunchKernelGGL(k_prepw, dim3((128 * 128 + 255) / 256), dim3(256), 0, stream, W2b, W2bt, 128, 128);

  // proj: x0 = pept @ Wp + bp
  hipLaunchKernelGGL((k_gemm<512, 0, 0>), dim3(gGemm), dim3(256), 0, stream,
                     pept, (const float*)nullptr, Wpt, bp, (const float*)nullptr, x0, N);

  // CSR by dst (built once, reused by both layers)
  hipMemsetAsync(deg, 0, (size_t)(N + 1) * 4, stream);
  hipLaunchKernelGGL(k_hist, dim3(gE), dim3(256), 0, stream, dstp, deg, E);
  hipLaunchKernelGGL(k_scan, dim3(1), dim3(1024), 0, stream, deg, off, cursor, N);
  hipLaunchKernelGGL(k_scatter, dim3(gE), dim3(256), 0, stream,
                     srcp, dstp, eattr, cursor, ep, E);

  // ---- layer a ----
  hipLaunchKernelGGL(k_agg, dim3(gAgg), dim3(256), 0, stream, x0, ep, off, emb, agg, N);
  hipLaunchKernelGGL((k_gemm<128, 1, 1>), dim3(gGemm), dim3(256), 0, stream,
                     x0, agg, W1at, b1a, (const float*)nullptr, tbh, N);
  hipLaunchKernelGGL((k_gemm<128, 2, 2>), dim3(gGemm), dim3(256), 0, stream,
                     tbh, (const float*)nullptr, W2at, b2a, x0, x1, N);

  // ---- layer b ----
  hipLaunchKernelGGL(k_agg, dim3(gAgg), dim3(256), 0, stream, x1, ep, off, emb, agg, N);
  hipLaunchKernelGGL((k_gemm<128, 1, 1>), dim3(gGemm), dim3(256), 0, stream,
                     x1, agg, W1bt, b1b, (const float*)nullptr, tbh, N);
  hipLaunchKernelGGL((k_gemm<128, 2, 2>), dim3(gGemm), dim3(256), 0, stream,
                     tbh, (const float*)nullptr, W2bt, b2b, x1, outp, N);
}

// Round 5
// 639.161 us; speedup vs baseline: 11.4616x; 1.5034x over previous
//
#include <hip/hip_runtime.h>

typedef unsigned short u16;
typedef __attribute__((ext_vector_type(8))) short short8v;
typedef __attribute__((ext_vector_type(4))) float f32x4;

__device__ __forceinline__ u16 f2b(float f) {
  union { float fv; unsigned int i; } v; v.fv = f;
  unsigned int x = v.i;
  return (u16)((x + 0x7FFFu + ((x >> 16) & 1u)) >> 16);
}

// ---------------- weight prep (all 5 weights, one launch) ----------------
__global__ __launch_bounds__(256) void k_prepw_all(
    const float* __restrict__ Wp, const float* __restrict__ W1a,
    const float* __restrict__ W2a, const float* __restrict__ W1b,
    const float* __restrict__ W2b,
    u16* __restrict__ Wpt, u16* __restrict__ W1at, u16* __restrict__ W2at,
    u16* __restrict__ W1bt, u16* __restrict__ W2bt)
{
  int idx = blockIdx.x * 256 + threadIdx.x;
  if (idx < 512 * 128) {
    int k = idx >> 7, c = idx & 127;
    Wpt[(size_t)c * 512 + k] = f2b(Wp[idx]);
    return;
  }
  idx -= 512 * 128;
  if (idx >= 4 * 128 * 128) return;
  int w = idx >> 14, r = idx & (128 * 128 - 1);
  int k = r >> 7, c = r & 127;
  const float* s = (w == 0) ? W1a : (w == 1) ? W2a : (w == 2) ? W1b : W2b;
  u16* d = (w == 0) ? W1at : (w == 1) ? W2at : (w == 2) ? W1bt : W2bt;
  d[(size_t)c * 128 + k] = f2b(s[r]);
}

// ---------------- MFMA GEMM: out[N,128] = A[N,KTOT] @ W[KTOT,128] (+bias...) ----
// STAGE: 0 = A fp32, 1 = A fp32 + agg, 2 = A bf16
// EPI:   0 = f32 out, 1 = relu -> bf16 out, 2 = (+xres) -> f32 out
template <int KTOT, int STAGE, int EPI>
__global__ __launch_bounds__(256) void k_gemm(
    const void* __restrict__ Ain, const float* __restrict__ agg,
    const u16* __restrict__ Wt, const float* __restrict__ bias,
    const float* __restrict__ xres, void* __restrict__ outp, int N)
{
  __shared__ u16 As[128 * 64];   // [r][k0..k0+64), row stride 128B, ^((r&7)<<4)
  __shared__ u16 Bs[128 * 64];
  const int t = threadIdx.x;
  const int row0 = blockIdx.x * 128;
  const int lane = t & 63;
  const int wave = t >> 6;
  const int wm = wave >> 1, wn = wave & 1;
  const int colg = lane & 15, rowg = lane >> 4;

  f32x4 acc[4][4];
#pragma unroll
  for (int ni = 0; ni < 4; ++ni) {
    float bc = bias[wn * 64 + ni * 16 + colg];
#pragma unroll
    for (int mi = 0; mi < 4; ++mi) acc[mi][ni] = (f32x4){bc, bc, bc, bc};
  }

  for (int k0 = 0; k0 < KTOT; k0 += 64) {
    if (STAGE <= 1) {
      const float* A = (const float*)Ain;
#pragma unroll
      for (int i = 0; i < 8; ++i) {
        int idx = t + i * 256;
        int r = idx >> 4, kq = idx & 15;
        float4 v = make_float4(0.f, 0.f, 0.f, 0.f);
        if (row0 + r < N) {
          v = *reinterpret_cast<const float4*>(A + (size_t)(row0 + r) * KTOT + k0 + kq * 4);
          if (STAGE == 1) {
            float4 av = *reinterpret_cast<const float4*>(agg + (size_t)(row0 + r) * 128 + k0 + kq * 4);
            v.x += av.x; v.y += av.y; v.z += av.z; v.w += av.w;
          }
        }
        ushort4 b;
        b.x = f2b(v.x); b.y = f2b(v.y); b.z = f2b(v.z); b.w = f2b(v.w);
        int byteoff = (r * 128 + kq * 8) ^ ((r & 7) << 4);
        *reinterpret_cast<ushort4*>((char*)As + byteoff) = b;
      }
    } else {
      const u16* A = (const u16*)Ain;
#pragma unroll
      for (int i = 0; i < 4; ++i) {
        int idx = t + i * 256;
        int r = idx >> 3, k8 = idx & 7;
        int4 v = make_int4(0, 0, 0, 0);
        if (row0 + r < N)
          v = *reinterpret_cast<const int4*>(A + (size_t)(row0 + r) * KTOT + k0 + k8 * 8);
        int byteoff = (r * 128 + k8 * 16) ^ ((r & 7) << 4);
        *reinterpret_cast<int4*>((char*)As + byteoff) = v;
      }
    }
#pragma unroll
    for (int i = 0; i < 4; ++i) {
      int idx = t + i * 256;
      int c = idx >> 3, k8 = idx & 7;
      int4 v = *reinterpret_cast<const int4*>(Wt + (size_t)c * KTOT + k0 + k8 * 8);
      int byteoff = (c * 128 + k8 * 16) ^ ((c & 7) << 4);
      *reinterpret_cast<int4*>((char*)Bs + byteoff) = v;
    }
    __syncthreads();
#pragma unroll
    for (int kk = 0; kk < 64; kk += 32) {
      short8v a[4], b[4];
#pragma unroll
      for (int mi = 0; mi < 4; ++mi) {
        int r = wm * 64 + mi * 16 + colg;
        int byteoff = (r * 128 + (kk + rowg * 8) * 2) ^ ((r & 7) << 4);
        a[mi] = *reinterpret_cast<const short8v*>((const char*)As + byteoff);
      }
#pragma unroll
      for (int ni = 0; ni < 4; ++ni) {
        int c = wn * 64 + ni * 16 + colg;
        int byteoff = (c * 128 + (kk + rowg * 8) * 2) ^ ((c & 7) << 4);
        b[ni] = *reinterpret_cast<const short8v*>((const char*)Bs + byteoff);
      }
#pragma unroll
      for (int mi = 0; mi < 4; ++mi)
#pragma unroll
        for (int ni = 0; ni < 4; ++ni)
          acc[mi][ni] = __builtin_amdgcn_mfma_f32_16x16x32_bf16(a[mi], b[ni], acc[mi][ni], 0, 0, 0);
    }
    __syncthreads();
  }

#pragma unroll
  for (int mi = 0; mi < 4; ++mi) {
#pragma unroll
    for (int j = 0; j < 4; ++j) {
      int row = row0 + wm * 64 + mi * 16 + rowg * 4 + j;
      if (row >= N) continue;
#pragma unroll
      for (int ni = 0; ni < 4; ++ni) {
        int col = wn * 64 + ni * 16 + colg;
        float v = acc[mi][ni][j];
        if (EPI == 1) {
          ((u16*)outp)[(size_t)row * 128 + col] = f2b(fmaxf(v, 0.f));
        } else {
          if (EPI == 2) v += xres[(size_t)row * 128 + col];
          ((float*)outp)[(size_t)row * 128 + col] = v;
        }
      }
    }
  }
}

// ---------------- CSR build ----------------
__global__ __launch_bounds__(256) void k_hist(
    const int* __restrict__ dst, int* __restrict__ deg, int nE)
{
  int e = blockIdx.x * 256 + threadIdx.x;
  if (e < nE) atomicAdd(&deg[dst[e]], 1);
}

// 3-phase scan: A = block partial sums (1024 deg each), B = scan partials,
// C = block-local scan + partial prefix -> off/cursor
__global__ __launch_bounds__(256) void k_scanA(
    const int* __restrict__ deg, int* __restrict__ part, int N)
{
  const int b = blockIdx.x, t = threadIdx.x;
  const int lane = t & 63, wave = t >> 6;
  int base = b * 1024 + t * 4;
  int s = 0;
#pragma unroll
  for (int i = 0; i < 4; ++i) { int j = base + i; if (j < N) s += deg[j]; }
  int v = s;
  for (int d = 1; d < 64; d <<= 1) { int u = __shfl_up(v, d); if (lane >= d) v += u; }
  __shared__ int wsum[4];
  if (lane == 63) wsum[wave] = v;
  __syncthreads();
  if (t == 0) part[b] = wsum[0] + wsum[1] + wsum[2] + wsum[3];
}

__global__ __launch_bounds__(128) void k_scanB(
    int* __restrict__ part, int* __restrict__ off, int NB, int N)
{
  __shared__ int ps[128];
  const int t = threadIdx.x;
  int v0 = (t < NB) ? part[t] : 0;
  ps[t] = v0;
  __syncthreads();
  for (int d = 1; d < 128; d <<= 1) {
    int u = (t >= d) ? ps[t - d] : 0;
    __syncthreads();
    ps[t] += u;
    __syncthreads();
  }
  if (t < NB) part[t] = ps[t] - v0;   // exclusive prefix
  if (t == 127) off[N] = ps[127];     // total
}

__global__ __launch_bounds__(256) void k_scanC(
    const int* __restrict__ deg, const int* __restrict__ part,
    int* __restrict__ off, int* __restrict__ cursor, int N)
{
  const int b = blockIdx.x, t = threadIdx.x;
  const int lane = t & 63, wave = t >> 6;
  int base = b * 1024 + t * 4;
  int d0 = 0, d1 = 0, d2 = 0, d3 = 0;
  if (base + 0 < N) d0 = deg[base + 0];
  if (base + 1 < N) d1 = deg[base + 1];
  if (base + 2 < N) d2 = deg[base + 2];
  if (base + 3 < N) d3 = deg[base + 3];
  int s = d0 + d1 + d2 + d3;
  int v = s;
  for (int dd = 1; dd < 64; dd <<= 1) { int u = __shfl_up(v, dd); if (lane >= dd) v += u; }
  int excl = v - s;
  __shared__ int wsum[4];
  if (lane == 63) wsum[wave] = v;
  __syncthreads();
  int wbase = 0;
  for (int w = 0; w < wave; ++w) wbase += wsum[w];
  int run = part[b] + wbase + excl;
  if (base + 0 < N) { off[base + 0] = run; cursor[base + 0] = run; run += d0; }
  if (base + 1 < N) { off[base + 1] = run; cursor[base + 1] = run; run += d1; }
  if (base + 2 < N) { off[base + 2] = run; cursor[base + 2] = run; run += d2; }
  if (base + 3 < N) { off[base + 3] = run; cursor[base + 3] = run; run += d3; }
}

__global__ __launch_bounds__(256) void k_scatter(
    const int* __restrict__ src, const int* __restrict__ dst,
    const int* __restrict__ attr, int* __restrict__ cursor,
    int* __restrict__ ep, int nE)
{
  int e = blockIdx.x * 256 + threadIdx.x;
  if (e < nE) {
    int p = atomicAdd(&cursor[dst[e]], 1);
    ep[p] = src[e] | (attr[e] << 17);
  }
}

// agg[i] = sum_{e in in-edges(i)} relu(x[src_e] + emb[attr_e]); one wave/node
__global__ __launch_bounds__(256) void k_agg(
    const float* __restrict__ x, const int* __restrict__ ep,
    const int* __restrict__ off, const float* __restrict__ emb,
    float* __restrict__ agg, int N)
{
  const int node = blockIdx.x * 4 + (threadIdx.x >> 6);
  if (node >= N) return;
  const int lane = threadIdx.x & 63;
  const int beg = off[node], end = off[node + 1];
  float ax = 0.f, ay = 0.f;
  int e = beg;
  for (; e + 2 <= end; e += 2) {
    int p0 = ep[e], p1 = ep[e + 1];
    int s0 = p0 & 0x1FFFF, a0 = p0 >> 17;
    int s1 = p1 & 0x1FFFF, a1 = p1 >> 17;
    float2 xv0 = *reinterpret_cast<const float2*>(x + (size_t)s0 * 128 + lane * 2);
    float2 ev0 = *reinterpret_cast<const float2*>(emb + (size_t)a0 * 128 + lane * 2);
    float2 xv1 = *reinterpret_cast<const float2*>(x + (size_t)s1 * 128 + lane * 2);
    float2 ev1 = *reinterpret_cast<const float2*>(emb + (size_t)a1 * 128 + lane * 2);
    ax += fmaxf(xv0.x + ev0.x, 0.f);
    ay += fmaxf(xv0.y + ev0.y, 0.f);
    ax += fmaxf(xv1.x + ev1.x, 0.f);
    ay += fmaxf(xv1.y + ev1.y, 0.f);
  }
  if (e < end) {
    int p = ep[e];
    int s = p & 0x1FFFF, a = p >> 17;
    float2 xv = *reinterpret_cast<const float2*>(x + (size_t)s * 128 + lane * 2);
    float2 ev = *reinterpret_cast<const float2*>(emb + (size_t)a * 128 + lane * 2);
    ax += fmaxf(xv.x + ev.x, 0.f);
    ay += fmaxf(xv.y + ev.y, 0.f);
  }
  float2* op = reinterpret_cast<float2*>(agg + (size_t)node * 128 + lane * 2);
  *op = make_float2(ax, ay);
}

// ---------------- launcher ----------------
extern "C" void kernel_launch(void* const* d_in, const int* in_sizes, int n_in,
                              void* d_out, int out_size, void* d_ws, size_t ws_size,
                              hipStream_t stream)
{
  const float* pept  = (const float*)d_in[0];
  const int*   eidx  = (const int*)d_in[1];
  const int*   eattr = (const int*)d_in[2];
  const float* Wp  = (const float*)d_in[3];
  const float* bp  = (const float*)d_in[4];
  const float* emb = (const float*)d_in[5];
  // d_in[6]=cls_token, d_in[7]=cls_edge: dead for the output (CLS node is never
  // a source and row N is dropped) -> skipped.
  const float* W1a = (const float*)d_in[8];
  const float* b1a = (const float*)d_in[9];
  const float* W2a = (const float*)d_in[10];
  const float* b2a = (const float*)d_in[11];
  const float* W1b = (const float*)d_in[12];
  const float* b1b = (const float*)d_in[13];
  const float* W2b = (const float*)d_in[14];
  const float* b2b = (const float*)d_in[15];

  const int N = in_sizes[0] / 512;
  const int E = in_sizes[1] / 2;
  const int* srcp = eidx;
  const int* dstp = eidx + E;

  char* ws = (char*)d_ws;
  const size_t rowBytes = (size_t)N * 128 * 4;
  float* agg = (float*)ws;                          // [N,128] f32
  float* x0  = (float*)(ws + rowBytes);             // [N,128] f32
  char*  p   = ws + 2 * rowBytes;
  u16* tbh   = (u16*)p;             p += (size_t)N * 128 * 2;   // bf16 hidden
  int* deg    = (int*)p;            p += (size_t)(N + 1) * 4;
  int* off    = (int*)p;            p += (size_t)(N + 1) * 4;
  int* cursor = (int*)p;            p += (size_t)N * 4;
  int* part   = (int*)p;            p += 128 * 4;
  int* ep     = (int*)p;            p += (size_t)E * 4;
  u16* Wpt  = (u16*)p;              p += (size_t)512 * 128 * 2;
  u16* W1at = (u16*)p;              p += (size_t)128 * 128 * 2;
  u16* W2at = (u16*)p;              p += (size_t)128 * 128 * 2;
  u16* W1bt = (u16*)p;              p += (size_t)128 * 128 * 2;
  u16* W2bt = (u16*)p;              p += (size_t)128 * 128 * 2;
  float* x1 = (float*)d_out;
  float* outp = (float*)d_out;

  const int gGemm = (N + 127) / 128;
  const int gE    = (E + 255) / 256;
  const int gAgg  = (N + 3) / 4;
  const int NB    = (N + 1023) / 1024;

  hipLaunchKernelGGL(k_prepw_all, dim3((512 * 128 + 4 * 128 * 128 + 255) / 256), dim3(256), 0, stream,
                     Wp, W1a, W2a, W1b, W2b, Wpt, W1at, W2at, W1bt, W2bt);

  // proj: x0 = pept @ Wp + bp
  hipLaunchKernelGGL((k_gemm<512, 0, 0>), dim3(gGemm), dim3(256), 0, stream,
                     pept, (const float*)nullptr, Wpt, bp, (const float*)nullptr, x0, N);

  // CSR by dst (built once, reused by both layers)
  hipMemsetAsync(deg, 0, (size_t)(N + 1) * 4, stream);
  hipLaunchKernelGGL(k_hist, dim3(gE), dim3(256), 0, stream, dstp, deg, E);
  hipLaunchKernelGGL(k_scanA, dim3(NB), dim3(256), 0, stream, deg, part, N);
  hipLaunchKernelGGL(k_scanB, dim3(1), dim3(128), 0, stream, part, off, NB, N);
  hipLaunchKernelGGL(k_scanC, dim3(NB), dim3(256), 0, stream, deg, part, off, cursor, N);
  hipLaunchKernelGGL(k_scatter, dim3(gE), dim3(256), 0, stream,
                     srcp, dstp, eattr, cursor, ep, E);

  // ---- layer a ----
  hipLaunchKernelGGL(k_agg, dim3(gAgg), dim3(256), 0, stream, x0, ep, off, emb, agg, N);
  hipLaunchKernelGGL((k_gemm<128, 1, 1>), dim3(gGemm), dim3(256), 0, stream,
                     x0, agg, W1at, b1a, (const float*)nullptr, tbh, N);
  hipLaunchKernelGGL((k_gemm<128, 2, 2>), dim3(gGemm), dim3(256), 0, stream,
                     tbh, (const float*)nullptr, W2at, b2a, x0, x1, N);

  // ---- layer b ----
  hipLaunchKernelGGL(k_agg, dim3(gAgg), dim3(256), 0, stream, x1, ep, off, emb, agg, N);
  hipLaunchKernelGGL((k_gemm<128, 1, 1>), dim3(gGemm), dim3(256), 0, stream,
                     x1, agg, W1bt, b1b, (const float*)nullptr, tbh, N);
  hipLaunchKernelGGL((k_gemm<128, 2, 2>), dim3(gGemm), dim3(256), 0, stream,
                     tbh, (const float*)nullptr, W2bt, b2b, x1, outp, N);
}

// Round 6
// 578.720 us; speedup vs baseline: 12.6587x; 1.1044x over previous
//
#include <hip/hip_runtime.h>

typedef unsigned short u16;
typedef __attribute__((ext_vector_type(8))) short short8v;
typedef __attribute__((ext_vector_type(4))) float f32x4;

__device__ __forceinline__ u16 f2b(float f) {
  union { float fv; unsigned int i; } v; v.fv = f;
  unsigned int x = v.i;
  return (u16)((x + 0x7FFFu + ((x >> 16) & 1u)) >> 16);
}
__device__ __forceinline__ float blo(unsigned u) {
  union { unsigned i; float f; } v; v.i = u << 16; return v.f;
}
__device__ __forceinline__ float bhi(unsigned u) {
  union { unsigned i; float f; } v; v.i = u & 0xFFFF0000u; return v.f;
}

// ---------------- weight + emb prep (one launch) ----------------
__global__ __launch_bounds__(256) void k_prepw_all(
    const float* __restrict__ Wp, const float* __restrict__ W1a,
    const float* __restrict__ W2a, const float* __restrict__ W1b,
    const float* __restrict__ W2b, const float* __restrict__ emb,
    u16* __restrict__ Wpt, u16* __restrict__ W1at, u16* __restrict__ W2at,
    u16* __restrict__ W1bt, u16* __restrict__ W2bt, u16* __restrict__ embb)
{
  int idx = blockIdx.x * 256 + threadIdx.x;
  if (idx < 512 * 128) {
    int k = idx >> 7, c = idx & 127;
    Wpt[(size_t)c * 512 + k] = f2b(Wp[idx]);
    return;
  }
  idx -= 512 * 128;
  if (idx < 4 * 128 * 128) {
    int w = idx >> 14, r = idx & (128 * 128 - 1);
    int k = r >> 7, c = r & 127;
    const float* s = (w == 0) ? W1a : (w == 1) ? W2a : (w == 2) ? W1b : W2b;
    u16* d = (w == 0) ? W1at : (w == 1) ? W2at : (w == 2) ? W1bt : W2bt;
    d[(size_t)c * 128 + k] = f2b(s[r]);
    return;
  }
  idx -= 4 * 128 * 128;
  if (idx < 100 * 128) embb[idx] = f2b(emb[idx]);
}

// ---------------- MFMA GEMM, BM=64: out[N,128] = A[N,KTOT] @ W[KTOT,128] ----
// STAGE: 0 = A fp32, 1 = A fp32 + agg, 2 = A bf16
// EPI:   0 = f32 out (+bf16 if WB), 1 = relu -> bf16 out, 2 = (+xres) -> f32 (+bf16 if WB)
template <int KTOT, int STAGE, int EPI, bool WB>
__global__ __launch_bounds__(256) void k_gemm(
    const void* __restrict__ Ain, const float* __restrict__ agg,
    const u16* __restrict__ Wt, const float* __restrict__ bias,
    const float* __restrict__ xres, void* __restrict__ outp,
    u16* __restrict__ outb, int N)
{
  __shared__ u16 As[64 * 64];    // [r][k0..k0+64), row stride 128B, ^((r&7)<<4)
  __shared__ u16 Bs[128 * 64];
  const int t = threadIdx.x;
  const int row0 = blockIdx.x * 64;
  const int lane = t & 63;
  const int wave = t >> 6;
  const int wm = wave >> 1, wn = wave & 1;   // 2x2 waves: 32 rows x 64 cols each
  const int colg = lane & 15, rowg = lane >> 4;

  f32x4 acc[2][4];
#pragma unroll
  for (int ni = 0; ni < 4; ++ni) {
    float bc = bias[wn * 64 + ni * 16 + colg];
#pragma unroll
    for (int mi = 0; mi < 2; ++mi) acc[mi][ni] = (f32x4){bc, bc, bc, bc};
  }

  for (int k0 = 0; k0 < KTOT; k0 += 64) {
    if (STAGE <= 1) {
      const float* A = (const float*)Ain;
#pragma unroll
      for (int i = 0; i < 4; ++i) {
        int idx = t + i * 256;            // 1024 float4 = 64 rows x 16
        int r = idx >> 4, kq = idx & 15;
        float4 v = make_float4(0.f, 0.f, 0.f, 0.f);
        if (row0 + r < N) {
          v = *reinterpret_cast<const float4*>(A + (size_t)(row0 + r) * KTOT + k0 + kq * 4);
          if (STAGE == 1) {
            float4 av = *reinterpret_cast<const float4*>(agg + (size_t)(row0 + r) * 128 + k0 + kq * 4);
            v.x += av.x; v.y += av.y; v.z += av.z; v.w += av.w;
          }
        }
        ushort4 b;
        b.x = f2b(v.x); b.y = f2b(v.y); b.z = f2b(v.z); b.w = f2b(v.w);
        int byteoff = (r * 128 + kq * 8) ^ ((r & 7) << 4);
        *reinterpret_cast<ushort4*>((char*)As + byteoff) = b;
      }
    } else {
      const u16* A = (const u16*)Ain;
#pragma unroll
      for (int i = 0; i < 2; ++i) {
        int idx = t + i * 256;            // 512 int4 = 64 rows x 8
        int r = idx >> 3, k8 = idx & 7;
        int4 v = make_int4(0, 0, 0, 0);
        if (row0 + r < N)
          v = *reinterpret_cast<const int4*>(A + (size_t)(row0 + r) * KTOT + k0 + k8 * 8);
        int byteoff = (r * 128 + k8 * 16) ^ ((r & 7) << 4);
        *reinterpret_cast<int4*>((char*)As + byteoff) = v;
      }
    }
#pragma unroll
    for (int i = 0; i < 4; ++i) {
      int idx = t + i * 256;              // 1024 int4 = 128 cols x 8
      int c = idx >> 3, k8 = idx & 7;
      int4 v = *reinterpret_cast<const int4*>(Wt + (size_t)c * KTOT + k0 + k8 * 8);
      int byteoff = (c * 128 + k8 * 16) ^ ((c & 7) << 4);
      *reinterpret_cast<int4*>((char*)Bs + byteoff) = v;
    }
    __syncthreads();
#pragma unroll
    for (int kk = 0; kk < 64; kk += 32) {
      short8v a[2], b[4];
#pragma unroll
      for (int mi = 0; mi < 2; ++mi) {
        int r = wm * 32 + mi * 16 + colg;
        int byteoff = (r * 128 + (kk + rowg * 8) * 2) ^ ((r & 7) << 4);
        a[mi] = *reinterpret_cast<const short8v*>((const char*)As + byteoff);
      }
#pragma unroll
      for (int ni = 0; ni < 4; ++ni) {
        int c = wn * 64 + ni * 16 + colg;
        int byteoff = (c * 128 + (kk + rowg * 8) * 2) ^ ((c & 7) << 4);
        b[ni] = *reinterpret_cast<const short8v*>((const char*)Bs + byteoff);
      }
#pragma unroll
      for (int mi = 0; mi < 2; ++mi)
#pragma unroll
        for (int ni = 0; ni < 4; ++ni)
          acc[mi][ni] = __builtin_amdgcn_mfma_f32_16x16x32_bf16(a[mi], b[ni], acc[mi][ni], 0, 0, 0);
    }
    __syncthreads();
  }

#pragma unroll
  for (int mi = 0; mi < 2; ++mi) {
#pragma unroll
    for (int j = 0; j < 4; ++j) {
      int row = row0 + wm * 32 + mi * 16 + rowg * 4 + j;
      if (row >= N) continue;
#pragma unroll
      for (int ni = 0; ni < 4; ++ni) {
        int col = wn * 64 + ni * 16 + colg;
        float v = acc[mi][ni][j];
        if (EPI == 1) {
          ((u16*)outp)[(size_t)row * 128 + col] = f2b(fmaxf(v, 0.f));
        } else {
          if (EPI == 2) v += xres[(size_t)row * 128 + col];
          ((float*)outp)[(size_t)row * 128 + col] = v;
          if (WB) outb[(size_t)row * 128 + col] = f2b(v);
        }
      }
    }
  }
}

// ---------------- CSR build ----------------
__global__ __launch_bounds__(256) void k_hist(
    const int* __restrict__ dst, int* __restrict__ deg, int nE)
{
  int e = blockIdx.x * 256 + threadIdx.x;
  if (e < nE) atomicAdd(&deg[dst[e]], 1);
}

__global__ __launch_bounds__(256) void k_scanA(
    const int* __restrict__ deg, int* __restrict__ part, int N)
{
  const int b = blockIdx.x, t = threadIdx.x;
  const int lane = t & 63, wave = t >> 6;
  int base = b * 1024 + t * 4;
  int s = 0;
#pragma unroll
  for (int i = 0; i < 4; ++i) { int j = base + i; if (j < N) s += deg[j]; }
  int v = s;
  for (int d = 1; d < 64; d <<= 1) { int u = __shfl_up(v, d); if (lane >= d) v += u; }
  __shared__ int wsum[4];
  if (lane == 63) wsum[wave] = v;
  __syncthreads();
  if (t == 0) part[b] = wsum[0] + wsum[1] + wsum[2] + wsum[3];
}

__global__ __launch_bounds__(128) void k_scanB(
    int* __restrict__ part, int* __restrict__ off, int NB, int N)
{
  __shared__ int ps[128];
  const int t = threadIdx.x;
  int v0 = (t < NB) ? part[t] : 0;
  ps[t] = v0;
  __syncthreads();
  for (int d = 1; d < 128; d <<= 1) {
    int u = (t >= d) ? ps[t - d] : 0;
    __syncthreads();
    ps[t] += u;
    __syncthreads();
  }
  if (t < NB) part[t] = ps[t] - v0;
  if (t == 127) off[N] = ps[127];
}

__global__ __launch_bounds__(256) void k_scanC(
    const int* __restrict__ deg, const int* __restrict__ part,
    int* __restrict__ off, int* __restrict__ cursor, int N)
{
  const int b = blockIdx.x, t = threadIdx.x;
  const int lane = t & 63, wave = t >> 6;
  int base = b * 1024 + t * 4;
  int d0 = 0, d1 = 0, d2 = 0, d3 = 0;
  if (base + 0 < N) d0 = deg[base + 0];
  if (base + 1 < N) d1 = deg[base + 1];
  if (base + 2 < N) d2 = deg[base + 2];
  if (base + 3 < N) d3 = deg[base + 3];
  int s = d0 + d1 + d2 + d3;
  int v = s;
  for (int dd = 1; dd < 64; dd <<= 1) { int u = __shfl_up(v, dd); if (lane >= dd) v += u; }
  int excl = v - s;
  __shared__ int wsum[4];
  if (lane == 63) wsum[wave] = v;
  __syncthreads();
  int wbase = 0;
  for (int w = 0; w < wave; ++w) wbase += wsum[w];
  int run = part[b] + wbase + excl;
  if (base + 0 < N) { off[base + 0] = run; cursor[base + 0] = run; run += d0; }
  if (base + 1 < N) { off[base + 1] = run; cursor[base + 1] = run; run += d1; }
  if (base + 2 < N) { off[base + 2] = run; cursor[base + 2] = run; run += d2; }
  if (base + 3 < N) { off[base + 3] = run; cursor[base + 3] = run; run += d3; }
}

__global__ __launch_bounds__(256) void k_scatter(
    const int* __restrict__ src, const int* __restrict__ dst,
    const int* __restrict__ attr, int* __restrict__ cursor,
    int* __restrict__ ep, int nE)
{
  int e = blockIdx.x * 256 + threadIdx.x;
  if (e < nE) {
    int p = atomicAdd(&cursor[dst[e]], 1);
    ep[p] = src[e] | (attr[e] << 17);
  }
}

// agg[i] = sum relu(xb[src] + embb[attr]); bf16 gather (256B rows), fp32 accum
__global__ __launch_bounds__(256) void k_agg(
    const u16* __restrict__ xb, const int* __restrict__ ep,
    const int* __restrict__ off, const u16* __restrict__ embb,
    float* __restrict__ agg, int N)
{
  const int node = blockIdx.x * 4 + (threadIdx.x >> 6);
  if (node >= N) return;
  const int lane = threadIdx.x & 63;
  const int beg = off[node], end = off[node + 1];
  float ax = 0.f, ay = 0.f;
  int e = beg;
  for (; e + 2 <= end; e += 2) {
    int p0 = ep[e], p1 = ep[e + 1];
    int s0 = p0 & 0x1FFFF, a0 = p0 >> 17;
    int s1 = p1 & 0x1FFFF, a1 = p1 >> 17;
    unsigned xu0 = *reinterpret_cast<const unsigned*>(xb + ((size_t)s0 << 7) + lane * 2);
    unsigned eu0 = *reinterpret_cast<const unsigned*>(embb + ((size_t)a0 << 7) + lane * 2);
    unsigned xu1 = *reinterpret_cast<const unsigned*>(xb + ((size_t)s1 << 7) + lane * 2);
    unsigned eu1 = *reinterpret_cast<const unsigned*>(embb + ((size_t)a1 << 7) + lane * 2);
    ax += fmaxf(blo(xu0) + blo(eu0), 0.f);
    ay += fmaxf(bhi(xu0) + bhi(eu0), 0.f);
    ax += fmaxf(blo(xu1) + blo(eu1), 0.f);
    ay += fmaxf(bhi(xu1) + bhi(eu1), 0.f);
  }
  if (e < end) {
    int p = ep[e];
    int s = p & 0x1FFFF, a = p >> 17;
    unsigned xu = *reinterpret_cast<const unsigned*>(xb + ((size_t)s << 7) + lane * 2);
    unsigned eu = *reinterpret_cast<const unsigned*>(embb + ((size_t)a << 7) + lane * 2);
    ax += fmaxf(blo(xu) + blo(eu), 0.f);
    ay += fmaxf(bhi(xu) + bhi(eu), 0.f);
  }
  float2* op = reinterpret_cast<float2*>(agg + (size_t)node * 128 + lane * 2);
  *op = make_float2(ax, ay);
}

// ---------------- launcher ----------------
extern "C" void kernel_launch(void* const* d_in, const int* in_sizes, int n_in,
                              void* d_out, int out_size, void* d_ws, size_t ws_size,
                              hipStream_t stream)
{
  const float* pept  = (const float*)d_in[0];
  const int*   eidx  = (const int*)d_in[1];
  const int*   eattr = (const int*)d_in[2];
  const float* Wp  = (const float*)d_in[3];
  const float* bp  = (const float*)d_in[4];
  const float* emb = (const float*)d_in[5];
  // d_in[6]=cls_token, d_in[7]=cls_edge: dead for the output (CLS node is never
  // a source and row N is dropped) -> skipped.
  const float* W1a = (const float*)d_in[8];
  const float* b1a = (const float*)d_in[9];
  const float* W2a = (const float*)d_in[10];
  const float* b2a = (const float*)d_in[11];
  const float* W1b = (const float*)d_in[12];
  const float* b1b = (const float*)d_in[13];
  const float* W2b = (const float*)d_in[14];
  const float* b2b = (const float*)d_in[15];

  const int N = in_sizes[0] / 512;
  const int E = in_sizes[1] / 2;
  const int* srcp = eidx;
  const int* dstp = eidx + E;

  char* ws = (char*)d_ws;
  const size_t rowBytes = (size_t)N * 128 * 4;
  float* agg = (float*)ws;                          // [N,128] f32
  float* x0  = (float*)(ws + rowBytes);             // [N,128] f32
  char*  p   = ws + 2 * rowBytes;
  u16* tbh   = (u16*)p;             p += (size_t)N * 128 * 2;   // bf16 hidden
  u16* xb    = (u16*)p;             p += (size_t)N * 128 * 2;   // bf16 x mirror
  int* deg    = (int*)p;            p += (size_t)(N + 1) * 4;
  int* off    = (int*)p;            p += (size_t)(N + 1) * 4;
  int* cursor = (int*)p;            p += (size_t)N * 4;
  int* part   = (int*)p;            p += 128 * 4;
  int* ep     = (int*)p;            p += (size_t)E * 4;
  u16* Wpt  = (u16*)p;              p += (size_t)512 * 128 * 2;
  u16* W1at = (u16*)p;              p += (size_t)128 * 128 * 2;
  u16* W2at = (u16*)p;              p += (size_t)128 * 128 * 2;
  u16* W1bt = (u16*)p;              p += (size_t)128 * 128 * 2;
  u16* W2bt = (u16*)p;              p += (size_t)128 * 128 * 2;
  u16* embb = (u16*)p;              p += (size_t)100 * 128 * 2;
  float* x1 = (float*)d_out;
  float* outp = (float*)d_out;

  const int gGemm = (N + 63) / 64;
  const int gE    = (E + 255) / 256;
  const int gAgg  = (N + 3) / 4;
  const int NB    = (N + 1023) / 1024;

  hipLaunchKernelGGL(k_prepw_all,
                     dim3((512 * 128 + 4 * 128 * 128 + 100 * 128 + 255) / 256), dim3(256), 0, stream,
                     Wp, W1a, W2a, W1b, W2b, emb, Wpt, W1at, W2at, W1bt, W2bt, embb);

  // proj: x0 = pept @ Wp + bp  (also emits bf16 mirror xb)
  hipLaunchKernelGGL((k_gemm<512, 0, 0, true>), dim3(gGemm), dim3(256), 0, stream,
                     pept, (const float*)nullptr, Wpt, bp, (const float*)nullptr, x0, xb, N);

  // CSR by dst (built once, reused by both layers)
  hipMemsetAsync(deg, 0, (size_t)(N + 1) * 4, stream);
  hipLaunchKernelGGL(k_hist, dim3(gE), dim3(256), 0, stream, dstp, deg, E);
  hipLaunchKernelGGL(k_scanA, dim3(NB), dim3(256), 0, stream, deg, part, N);
  hipLaunchKernelGGL(k_scanB, dim3(1), dim3(128), 0, stream, part, off, NB, N);
  hipLaunchKernelGGL(k_scanC, dim3(NB), dim3(256), 0, stream, deg, part, off, cursor, N);
  hipLaunchKernelGGL(k_scatter, dim3(gE), dim3(256), 0, stream,
                     srcp, dstp, eattr, cursor, ep, E);

  // ---- layer a ----
  hipLaunchKernelGGL(k_agg, dim3(gAgg), dim3(256), 0, stream, xb, ep, off, embb, agg, N);
  hipLaunchKernelGGL((k_gemm<128, 1, 1, false>), dim3(gGemm), dim3(256), 0, stream,
                     x0, agg, W1at, b1a, (const float*)nullptr, tbh, (u16*)nullptr, N);
  hipLaunchKernelGGL((k_gemm<128, 2, 2, true>), dim3(gGemm), dim3(256), 0, stream,
                     tbh, (const float*)nullptr, W2at, b2a, x0, x1, xb, N);

  // ---- layer b ----
  hipLaunchKernelGGL(k_agg, dim3(gAgg), dim3(256), 0, stream, xb, ep, off, embb, agg, N);
  hipLaunchKernelGGL((k_gemm<128, 1, 1, false>), dim3(gGemm), dim3(256), 0, stream,
                     x1, agg, W1bt, b1b, (const float*)nullptr, tbh, (u16*)nullptr, N);
  hipLaunchKernelGGL((k_gemm<128, 2, 2, false>), dim3(gGemm), dim3(256), 0, stream,
                     tbh, (const float*)nullptr, W2bt, b2b, x1, outp, (u16*)nullptr, N);
}